// Round 1
// baseline (4139.441 us; speedup 1.0000x reference)
//
#include <hip/hip_runtime.h>

// PositionConv: B=4, CIN=COUT=64, K=3, D=H=W=64
// Stage 1: w[b][co][ci][t] = sum_c pos_emb[b][n][c] * W_pos[c][f] + b_pos[f]
//          where n = co*3 + (ci*27+t)/576, f = (ci*27+t)%576   (row-major reshape)
// Stage 2: direct 3D conv, pad=1, stride=1 (correlation, no flip)

#define NB   4
#define NC   64          // CIN == COUT
#define KT   27          // 3*3*3 taps
#define DHW  64
#define YT   4           // y rows per block

// ---------------- Stage 1: dynamic weight build ----------------
__global__ void pos_weight_kernel(const float* __restrict__ pos_emb,  // [4][192][64]
                                  const float* __restrict__ W_pos,    // [64][576]
                                  const float* __restrict__ b_pos,    // [576]
                                  float* __restrict__ w)              // [4][64][64][27]
{
    int idx = blockIdx.x * 256 + threadIdx.x;          // [0, 4*64*64*27)
    if (idx >= NB * NC * NC * KT) return;
    int t  = idx % KT;
    int ci = (idx / KT) % NC;
    int co = (idx / (KT * NC)) % NC;
    int b  = idx / (KT * NC * NC);

    int r = ci * KT + t;             // [0, 1728)
    int n = co * 3 + r / 576;        // [0, 192)
    int f = r % 576;

    const float* pe = pos_emb + ((size_t)b * 192 + n) * 64;
    float acc = b_pos[f];
    #pragma unroll 8
    for (int c = 0; c < 64; ++c)
        acc += pe[c] * W_pos[c * 576 + f];
    w[idx] = acc;
}

// ---------------- Stage 2: direct conv ----------------
// grid: b(4) * z(64) * ytile(16); block: 256 = x(64) * coq(4)
// each thread: 16 co (co = coq*16+i) x 4 y x 1 x  => 64 accumulators
__global__ __launch_bounds__(256, 2)
void conv_kernel(const float* __restrict__ x,    // [4][64][64][64][64]
                 const float* __restrict__ w,    // [4][64][64][27]
                 float* __restrict__ out)        // [4][64][64][64][64]
{
    const int bid = blockIdx.x;
    const int yt = bid & 15;                 // 16 y-tiles
    const int z  = (bid >> 4) & 63;
    const int b  = bid >> 10;
    const int y0 = yt * YT;

    const int tid = threadIdx.x;
    const int lx  = tid & 63;                // x coordinate
    const int coq = tid >> 6;                // 0..3

    __shared__ float xs[3][YT + 2][68];      // halo tile, padded rows
    __shared__ float ws[NC][28];             // all-co weights for current ci

    float acc[16][YT];
    #pragma unroll
    for (int i = 0; i < 16; ++i)
        #pragma unroll
        for (int y = 0; y < YT; ++y) acc[i][y] = 0.0f;

    const float* xb = x + (((size_t)b) * NC << 18);          // x[b]
    const float* wb = w + ((size_t)b) * NC * NC * KT;        // w[b]

    for (int ci = 0; ci < NC; ++ci) {
        // ---- stage x halo tile: 3 z-slices x 6 y-rows x 66 x-vals ----
        const float* xc = xb + ((size_t)ci << 18);
        for (int i = tid; i < 3 * (YT + 2) * 66; i += 256) {
            int xx  = i % 66;
            int row = (i / 66) % (YT + 2);
            int zz  = i / (66 * (YT + 2));
            int gz = z + zz - 1, gy = y0 + row - 1, gx = xx - 1;
            float v = 0.0f;
            if ((unsigned)gz < 64u && (unsigned)gy < 64u && (unsigned)gx < 64u)
                v = xc[((gz << 6) + gy) * 64 + gx];
            xs[zz][row][xx] = v;
        }
        // ---- stage weights for this ci: w[b][co][ci][0..26] for all co ----
        const float* wc = wb + (size_t)ci * KT;
        for (int i = tid; i < NC * KT; i += 256) {
            int t  = i % KT;
            int co = i / KT;
            ws[co][t] = wc[(size_t)co * NC * KT + t];
        }
        __syncthreads();

        // ---- pull x neighborhood into registers: 3z x 6rows x 3kw = 54 ----
        float xr[3][YT + 2][3];
        #pragma unroll
        for (int zz = 0; zz < 3; ++zz)
            #pragma unroll
            for (int row = 0; row < YT + 2; ++row)
                #pragma unroll
                for (int kw = 0; kw < 3; ++kw)
                    xr[zz][row][kw] = xs[zz][row][lx + kw];

        // ---- accumulate: 16 co x 4 y x 27 taps ----
        #pragma unroll
        for (int i = 0; i < 16; ++i) {
            const int co = (coq << 4) + i;
            float wv[28];
            const float4* wr = (const float4*)(&ws[co][0]);
            #pragma unroll
            for (int q = 0; q < 7; ++q)
                *(float4*)&wv[4 * q] = wr[q];          // wave-uniform broadcast reads
            #pragma unroll
            for (int y = 0; y < YT; ++y) {
                float s = acc[i][y];
                #pragma unroll
                for (int kd = 0; kd < 3; ++kd)
                    #pragma unroll
                    for (int kh = 0; kh < 3; ++kh)
                        #pragma unroll
                        for (int kw = 0; kw < 3; ++kw)
                            s += xr[kd][y + kh][kw] * wv[kd * 9 + kh * 3 + kw];
                acc[i][y] = s;
            }
        }
        __syncthreads();
    }

    // ---- write out: [b][co][z][y][x] ----
    #pragma unroll
    for (int i = 0; i < 16; ++i) {
        const int co = (coq << 4) + i;
        float* ob = out + ((((((size_t)b * NC + co) << 6) + z) << 6) + y0) * 64 + lx;
        #pragma unroll
        for (int y = 0; y < YT; ++y)
            ob[(size_t)y * 64] = acc[i][y];
    }
}

extern "C" void kernel_launch(void* const* d_in, const int* in_sizes, int n_in,
                              void* d_out, int out_size, void* d_ws, size_t ws_size,
                              hipStream_t stream) {
    const float* x       = (const float*)d_in[0];   // [4][64][64][64][64]
    const float* pos_emb = (const float*)d_in[1];   // [4][192][64]
    const float* W_pos   = (const float*)d_in[2];   // [64][576]
    const float* b_pos   = (const float*)d_in[3];   // [576]
    float* out = (float*)d_out;
    float* w   = (float*)d_ws;                      // 4*64*64*27 floats = 1.77 MB

    // Stage 1: build dynamic weights (re-built every call; ws is re-poisoned)
    {
        int total = NB * NC * NC * KT;              // 442368
        int blocks = (total + 255) / 256;
        pos_weight_kernel<<<blocks, 256, 0, stream>>>(pos_emb, W_pos, b_pos, w);
    }
    // Stage 2: conv
    {
        int blocks = NB * DHW * (DHW / YT);         // 4*64*16 = 4096
        conv_kernel<<<blocks, 256, 0, stream>>>(x, w, out);
    }
}